// Round 2
// baseline (202.664 us; speedup 1.0000x reference)
//
#include <hip/hip_runtime.h>
#include <math.h>

// Problem constants: L=4, B=8, Ns=1200, Nl=128, C=768, H=W=448, strides 8/28
constexpr int L_  = 4;
constexpr int B_  = 8;
constexpr int NS  = 1200;
constexpr int NL  = 128;
constexpr int C_  = 768;
constexpr int H_  = 448;
constexpr int W_  = 448;
constexpr int NVS = 3136;   // (448/8)^2
constexpr int NVL = 256;    // (448/28)^2
constexpr int ROWS_S = L_ * B_ * NS;   // 38400
constexpr int ROWS_L = L_ * B_ * NL;   // 4096
constexpr int RPB    = 16;             // rows per block in k_dist (4 waves x 4 rows)
constexpr int BLKS_S = ROWS_S / RPB;   // 2400
constexpr int BLKS_L = ROWS_L / RPB;   // 256

// ---------------------------------------------------------------------------
// K1: valid masks from f_k + zero the completion counter.
__global__ __launch_bounds__(256)
void k_valid(const float* __restrict__ f_k,
             unsigned char* __restrict__ valid_s,
             unsigned char* __restrict__ valid_l,
             int* __restrict__ counter) {
    int i = blockIdx.x * 256 + threadIdx.x;
    if (i == 0) *counter = 0;
    if (i < B_ * NVS) {
        int b = i / NVS, p = i - b * NVS;
        int r = p / 56, c = p - r * 56;
        valid_s[i] = (f_k[b * H_ * W_ + r * 8 * W_ + c * 8] > 0.f) ? 1 : 0;
    } else {
        int j = i - B_ * NVS;
        if (j < B_ * NVL) {
            int b = j / NVL, p = j - b * NVL;
            int r = p / 16, c = p - r * 16;
            valid_l[j] = (f_k[b * H_ * W_ + r * 28 * W_ + c * 28] > 0.f) ? 1 : 0;
        }
    }
}

// ---------------------------------------------------------------------------
// K2: distances + nonzero flags. One block = 16 consecutive rows of ONE (l,b)
// (1200 % 16 == 0, 128 % 16 == 0 -> never straddles). Each wave: anchor
// loaded once (3 float4), then 4 rows with all 12 sel float4s preloaded.
__global__ __launch_bounds__(256)
void k_dist(const float* __restrict__ sel_s, const float* __restrict__ sel_l,
            const float* __restrict__ ker_s, const float* __restrict__ ker_l,
            float* __restrict__ d_s, float* __restrict__ d_l,
            unsigned char* __restrict__ nz_s, unsigned char* __restrict__ nz_l) {
    const int lane = threadIdx.x & 63;
    const int wid  = threadIdx.x >> 6;
    const int blk  = blockIdx.x;

    const float* sel; const float* ker; float* dout; unsigned char* nzout;
    int base, N;
    if (blk < BLKS_S) { base = blk * RPB;            N = NS; sel = sel_s; ker = ker_s; dout = d_s; nzout = nz_s; }
    else              { base = (blk - BLKS_S) * RPB; N = NL; sel = sel_l; ker = ker_l; dout = d_l; nzout = nz_l; }
    const int lb = base / N;   // block-uniform

    const float4* __restrict__ arow = (const float4*)(ker + lb * C_);
    float4 a0 = arow[lane], a1 = arow[64 + lane], a2 = arow[128 + lane];

    const int r0 = base + wid * 4;
    float4 s[4][3];
#pragma unroll
    for (int k = 0; k < 4; ++k) {
        const float4* __restrict__ srow = (const float4*)(sel + (r0 + k) * C_);
        s[k][0] = srow[lane];
        s[k][1] = srow[64 + lane];
        s[k][2] = srow[128 + lane];
    }
#pragma unroll
    for (int k = 0; k < 4; ++k) {
        float acc = 0.f; int nz = 0;
        {
            float4 sv = s[k][0];
            float dx = a0.x - sv.x, dy = a0.y - sv.y, dz = a0.z - sv.z, dw = a0.w - sv.w;
            acc += dx*dx + dy*dy + dz*dz + dw*dw;
            nz |= (sv.x != 0.f) || (sv.y != 0.f) || (sv.z != 0.f) || (sv.w != 0.f);
        }
        {
            float4 sv = s[k][1];
            float dx = a1.x - sv.x, dy = a1.y - sv.y, dz = a1.z - sv.z, dw = a1.w - sv.w;
            acc += dx*dx + dy*dy + dz*dz + dw*dw;
            nz |= (sv.x != 0.f) || (sv.y != 0.f) || (sv.z != 0.f) || (sv.w != 0.f);
        }
        {
            float4 sv = s[k][2];
            float dx = a2.x - sv.x, dy = a2.y - sv.y, dz = a2.z - sv.z, dw = a2.w - sv.w;
            acc += dx*dx + dy*dy + dz*dz + dw*dw;
            nz |= (sv.x != 0.f) || (sv.y != 0.f) || (sv.z != 0.f) || (sv.w != 0.f);
        }
#pragma unroll
        for (int off = 32; off >= 1; off >>= 1) acc += __shfl_xor(acc, off, 64);
        int wnz = __any(nz);
        if (lane == 0) {
            dout[r0 + k]  = sqrtf(acc);
            nzout[r0 + k] = (unsigned char)(wnz ? 1 : 0);
        }
    }
}

// ---------------------------------------------------------------------------
// K3: fused stats + final. 32 blocks, one per (l,b); each handles BOTH scales.
// col_valid computed inline into LDS (OR of nz over b). Last-done block
// reduces the 32 results and writes the scalar.
__global__ __launch_bounds__(256)
void k_stats(const float* __restrict__ d_s, const float* __restrict__ d_l,
             const int* __restrict__ idx_s, const int* __restrict__ idx_l,
             const unsigned char* __restrict__ valid_s,
             const unsigned char* __restrict__ valid_l,
             const unsigned char* __restrict__ nz_s,
             const unsigned char* __restrict__ nz_l,
             float* __restrict__ res,      // 64 floats: (total, times) per block
             int* __restrict__ counter,
             float* __restrict__ out) {
    const int blk = blockIdx.x;        // l*8 + b
    const int l = blk >> 3, b = blk & 7;
    const int tid = threadIdx.x;

    __shared__ unsigned char cvs[NS];
    __shared__ unsigned char cvl[NL];
    for (int n = tid; n < NS; n += 256) {
        int v = 0;
        for (int bb = 0; bb < B_; ++bb) v |= nz_s[(l * B_ + bb) * NS + n];
        cvs[n] = (unsigned char)v;
    }
    for (int n = tid; n < NL; n += 256) {
        int v = 0;
        for (int bb = 0; bb < B_; ++bb) v |= nz_l[(l * B_ + bb) * NL + n];
        cvl[n] = (unsigned char)v;
    }
    __syncthreads();

    float sp[2] = {0.f, 0.f}, sn[2] = {0.f, 0.f};
    int   cp[2] = {0, 0},     cn[2] = {0, 0};
#pragma unroll
    for (int sc = 0; sc < 2; ++sc) {
        const int N  = sc ? NL : NS;
        const int Nv = sc ? NVL : NVS;
        const float* d           = sc ? d_l : d_s;
        const int* idx           = sc ? idx_l : idx_s;
        const unsigned char* val = sc ? valid_l : valid_s;
        const unsigned char* cv  = sc ? cvl : cvs;
        const int rb = blk * N;
        for (int n = tid; n < N; n += 256) {
            float dv   = d[rb + n];
            int member = val[b * Nv + idx[rb + n]];
            int colv   = cv[n];
            int pos = member & colv;
            int neg = (member ^ 1) & colv;
            sp[sc] += pos ? dv : 0.f;
            sn[sc] += neg ? dv : 0.f;
            cp[sc] += pos;
            cn[sc] += neg;
        }
    }
#pragma unroll
    for (int off = 32; off >= 1; off >>= 1) {
#pragma unroll
        for (int sc = 0; sc < 2; ++sc) {
            sp[sc] += __shfl_xor(sp[sc], off, 64);
            sn[sc] += __shfl_xor(sn[sc], off, 64);
            cp[sc] += __shfl_xor(cp[sc], off, 64);
            cn[sc] += __shfl_xor(cn[sc], off, 64);
        }
    }
    __shared__ float wsp[2][4], wsn[2][4];
    __shared__ int   wcp[2][4], wcn[2][4];
    __shared__ int   islast;
    const int wid = tid >> 6, lane = tid & 63;
    if (lane == 0) {
#pragma unroll
        for (int sc = 0; sc < 2; ++sc) {
            wsp[sc][wid] = sp[sc]; wsn[sc][wid] = sn[sc];
            wcp[sc][wid] = cp[sc]; wcn[sc][wid] = cn[sc];
        }
    }
    if (tid == 0) islast = 0;
    __syncthreads();

    if (tid == 0) {
        float lossv[2]; int actv[2];
#pragma unroll
        for (int sc = 0; sc < 2; ++sc) {
            float SP = 0.f, SN = 0.f; int CP = 0, CN = 0;
            for (int w = 0; w < 4; ++w) { SP += wsp[sc][w]; SN += wsn[sc][w]; CP += wcp[sc][w]; CN += wcn[sc][w]; }
            float ap = SP / (float)(CP > 0 ? CP : 1);
            float an = SN / (float)(CN > 0 ? CN : 1);
            float x  = ap - an;
            lossv[sc] = fmaxf(x, 0.f) + log1pf(expf(-fabsf(x)));
            actv[sc]  = (CP > 0 && CN > 0) ? 1 : 0;
        }
        actv[1] &= actv[0];
        float contrib = (actv[0] ? lossv[0] : 0.f) + (actv[1] ? lossv[1] : 0.f);
        float times   = (float)(actv[0] + actv[1]);
        __hip_atomic_store(&res[2 * blk],     contrib, __ATOMIC_RELAXED, __HIP_MEMORY_SCOPE_AGENT);
        __hip_atomic_store(&res[2 * blk + 1], times,   __ATOMIC_RELAXED, __HIP_MEMORY_SCOPE_AGENT);
        int old = __hip_atomic_fetch_add(counter, 1, __ATOMIC_ACQ_REL, __HIP_MEMORY_SCOPE_AGENT);
        islast = (old == 31) ? 1 : 0;
    }
    __syncthreads();
    if (islast && wid == 0) {
        float total = 0.f, times = 0.f;
        if (lane < 32) {
            total = __hip_atomic_load(&res[2 * lane],     __ATOMIC_RELAXED, __HIP_MEMORY_SCOPE_AGENT);
            times = __hip_atomic_load(&res[2 * lane + 1], __ATOMIC_RELAXED, __HIP_MEMORY_SCOPE_AGENT);
        }
#pragma unroll
        for (int off = 32; off >= 1; off >>= 1) {
            total += __shfl_xor(total, off, 64);
            times += __shfl_xor(times, off, 64);
        }
        if (lane == 0) out[0] = (times > 0.f) ? (total / times) : 0.f;
    }
}

// ---------------------------------------------------------------------------
extern "C" void kernel_launch(void* const* d_in, const int* in_sizes, int n_in,
                              void* d_out, int out_size, void* d_ws, size_t ws_size,
                              hipStream_t stream) {
    const float* sel_s = (const float*)d_in[0];
    const int*   idx_s = (const int*)  d_in[1];
    const float* sel_l = (const float*)d_in[2];
    const int*   idx_l = (const int*)  d_in[3];
    const float* ker_s = (const float*)d_in[4];
    const float* ker_l = (const float*)d_in[5];
    const float* f_k   = (const float*)d_in[6];
    float* out = (float*)d_out;

    char* base = (char*)d_ws;
    size_t o = 0;
    auto alloc = [&](size_t sz) -> char* {
        char* p = base + o;
        o += (sz + 255) & ~(size_t)255;
        return p;
    };
    unsigned char* valid_s = (unsigned char*)alloc(B_ * NVS);
    unsigned char* valid_l = (unsigned char*)alloc(B_ * NVL);
    unsigned char* nz_s    = (unsigned char*)alloc(ROWS_S);
    unsigned char* nz_l    = (unsigned char*)alloc(ROWS_L);
    float* d_s   = (float*)alloc(ROWS_S * sizeof(float));
    float* d_l   = (float*)alloc(ROWS_L * sizeof(float));
    float* res   = (float*)alloc(64 * sizeof(float));
    int*   cnt   = (int*)alloc(sizeof(int));

    k_valid<<<(B_ * NVS + B_ * NVL + 255) / 256, 256, 0, stream>>>(f_k, valid_s, valid_l, cnt);
    k_dist<<<BLKS_S + BLKS_L, 256, 0, stream>>>(sel_s, sel_l, ker_s, ker_l, d_s, d_l, nz_s, nz_l);
    k_stats<<<32, 256, 0, stream>>>(d_s, d_l, idx_s, idx_l, valid_s, valid_l,
                                    nz_s, nz_l, res, cnt, out);
}

// Round 3
// 197.741 us; speedup vs baseline: 1.0249x; 1.0249x over previous
//
#include <hip/hip_runtime.h>
#include <math.h>

// Problem constants: L=4, B=8, Ns=1200, Nl=128, C=768, H=W=448, strides 8/28
constexpr int L_  = 4;
constexpr int B_  = 8;
constexpr int NS  = 1200;
constexpr int NL  = 128;
constexpr int C_  = 768;
constexpr int H_  = 448;
constexpr int W_  = 448;
constexpr int NVS = 3136;   // (448/8)^2
constexpr int NVL = 256;    // (448/28)^2
constexpr int ROWS_S = L_ * B_ * NS;   // 38400
constexpr int ROWS_L = L_ * B_ * NL;   // 4096
constexpr int RPB    = 16;             // rows per block in k_dist
constexpr int BLKS_S = ROWS_S / RPB;   // 2400
constexpr int BLKS_L = ROWS_L / RPB;   // 256
constexpr int CVBYTES = L_ * NS + L_ * NL;  // 5312

// ---------------------------------------------------------------------------
// K1: valid masks from f_k + zero cv buffers + zero completion counter.
__global__ __launch_bounds__(256)
void k_prep(const float* __restrict__ f_k,
            unsigned char* __restrict__ valid_s,
            unsigned char* __restrict__ valid_l,
            unsigned char* __restrict__ cv,      // cv_s (L*NS) then cv_l (L*NL)
            int* __restrict__ counter) {
    int i = blockIdx.x * 256 + threadIdx.x;
    if (i == 0) *counter = 0;
    if (i < CVBYTES) cv[i] = 0;
    if (i < B_ * NVS) {
        int b = i / NVS, p = i - b * NVS;
        int r = p / 56, c = p - r * 56;
        valid_s[i] = (f_k[b * H_ * W_ + r * 8 * W_ + c * 8] > 0.f) ? 1 : 0;
    } else {
        int j = i - B_ * NVS;
        if (j < B_ * NVL) {
            int b = j / NVL, p = j - b * NVL;
            int r = p / 16, c = p - r * 16;
            valid_l[j] = (f_k[b * H_ * W_ + r * 28 * W_ + c * 28] > 0.f) ? 1 : 0;
        }
    }
}

// ---------------------------------------------------------------------------
// K2: distances + col_valid stores. One block = 16 consecutive rows of ONE
// (l,b). Anchor loaded once per wave; rows' nonzero flag stored directly into
// cv[l*N+n] (plain store of 1 -- benign race, all writers store 1).
__global__ __launch_bounds__(256)
void k_dist(const float* __restrict__ sel_s, const float* __restrict__ sel_l,
            const float* __restrict__ ker_s, const float* __restrict__ ker_l,
            float* __restrict__ d_s, float* __restrict__ d_l,
            unsigned char* __restrict__ cv_s, unsigned char* __restrict__ cv_l) {
    const int lane = threadIdx.x & 63;
    const int wid  = threadIdx.x >> 6;
    const int blk  = blockIdx.x;

    const float* sel; const float* ker; float* dout; unsigned char* cvout;
    int base, N;
    if (blk < BLKS_S) { base = blk * RPB;            N = NS; sel = sel_s; ker = ker_s; dout = d_s; cvout = cv_s; }
    else              { base = (blk - BLKS_S) * RPB; N = NL; sel = sel_l; ker = ker_l; dout = d_l; cvout = cv_l; }
    const int lb = base / N;           // block-uniform
    const int l  = lb >> 3;            // B_ == 8

    const float4* __restrict__ arow = (const float4*)(ker + lb * C_);
    float4 a0 = arow[lane], a1 = arow[64 + lane], a2 = arow[128 + lane];

    const int r0 = base + wid * 4;
    float4 s[4][3];
#pragma unroll
    for (int k = 0; k < 4; ++k) {
        const float4* __restrict__ srow = (const float4*)(sel + (r0 + k) * C_);
        s[k][0] = srow[lane];
        s[k][1] = srow[64 + lane];
        s[k][2] = srow[128 + lane];
    }
#pragma unroll
    for (int k = 0; k < 4; ++k) {
        float acc = 0.f; int nz = 0;
        {
            float4 sv = s[k][0];
            float dx = a0.x - sv.x, dy = a0.y - sv.y, dz = a0.z - sv.z, dw = a0.w - sv.w;
            acc += dx*dx + dy*dy + dz*dz + dw*dw;
            nz |= (sv.x != 0.f) || (sv.y != 0.f) || (sv.z != 0.f) || (sv.w != 0.f);
        }
        {
            float4 sv = s[k][1];
            float dx = a1.x - sv.x, dy = a1.y - sv.y, dz = a1.z - sv.z, dw = a1.w - sv.w;
            acc += dx*dx + dy*dy + dz*dz + dw*dw;
            nz |= (sv.x != 0.f) || (sv.y != 0.f) || (sv.z != 0.f) || (sv.w != 0.f);
        }
        {
            float4 sv = s[k][2];
            float dx = a2.x - sv.x, dy = a2.y - sv.y, dz = a2.z - sv.z, dw = a2.w - sv.w;
            acc += dx*dx + dy*dy + dz*dz + dw*dw;
            nz |= (sv.x != 0.f) || (sv.y != 0.f) || (sv.z != 0.f) || (sv.w != 0.f);
        }
#pragma unroll
        for (int off = 32; off >= 1; off >>= 1) acc += __shfl_xor(acc, off, 64);
        int wnz = __any(nz);
        if (lane == 0) {
            const int r = r0 + k;
            dout[r] = sqrtf(acc);
            if (wnz) cvout[l * N + (r - lb * N)] = 1;
        }
    }
}

// ---------------------------------------------------------------------------
// K3: fused stats + final. 32 blocks, one per (l,b); each handles BOTH
// scales. Last-done block reduces the 32 results and writes the scalar.
__global__ __launch_bounds__(256)
void k_stats(const float* __restrict__ d_s, const float* __restrict__ d_l,
             const int* __restrict__ idx_s, const int* __restrict__ idx_l,
             const unsigned char* __restrict__ valid_s,
             const unsigned char* __restrict__ valid_l,
             const unsigned char* __restrict__ cv_s,
             const unsigned char* __restrict__ cv_l,
             float* __restrict__ res,      // 64 floats: (total, times) per block
             int* __restrict__ counter,
             float* __restrict__ out) {
    const int blk = blockIdx.x;        // l*8 + b
    const int l = blk >> 3, b = blk & 7;
    const int tid = threadIdx.x;

    float sp[2] = {0.f, 0.f}, sn[2] = {0.f, 0.f};
    int   cp[2] = {0, 0},     cn[2] = {0, 0};
#pragma unroll
    for (int sc = 0; sc < 2; ++sc) {
        const int N  = sc ? NL : NS;
        const int Nv = sc ? NVL : NVS;
        const float* d           = sc ? d_l : d_s;
        const int* idx           = sc ? idx_l : idx_s;
        const unsigned char* val = sc ? valid_l : valid_s;
        const unsigned char* cv  = sc ? cv_l : cv_s;
        const int rb = blk * N;
        for (int n = tid; n < N; n += 256) {
            float dv   = d[rb + n];
            int member = val[b * Nv + idx[rb + n]];
            int colv   = cv[l * N + n];
            int pos = member & colv;
            int neg = (member ^ 1) & colv;
            sp[sc] += pos ? dv : 0.f;
            sn[sc] += neg ? dv : 0.f;
            cp[sc] += pos;
            cn[sc] += neg;
        }
    }
#pragma unroll
    for (int off = 32; off >= 1; off >>= 1) {
#pragma unroll
        for (int sc = 0; sc < 2; ++sc) {
            sp[sc] += __shfl_xor(sp[sc], off, 64);
            sn[sc] += __shfl_xor(sn[sc], off, 64);
            cp[sc] += __shfl_xor(cp[sc], off, 64);
            cn[sc] += __shfl_xor(cn[sc], off, 64);
        }
    }
    __shared__ float wsp[2][4], wsn[2][4];
    __shared__ int   wcp[2][4], wcn[2][4];
    __shared__ int   islast;
    const int wid = tid >> 6, lane = tid & 63;
    if (lane == 0) {
#pragma unroll
        for (int sc = 0; sc < 2; ++sc) {
            wsp[sc][wid] = sp[sc]; wsn[sc][wid] = sn[sc];
            wcp[sc][wid] = cp[sc]; wcn[sc][wid] = cn[sc];
        }
    }
    if (tid == 0) islast = 0;
    __syncthreads();

    if (tid == 0) {
        float lossv[2]; int actv[2];
#pragma unroll
        for (int sc = 0; sc < 2; ++sc) {
            float SP = 0.f, SN = 0.f; int CP = 0, CN = 0;
            for (int w = 0; w < 4; ++w) { SP += wsp[sc][w]; SN += wsn[sc][w]; CP += wcp[sc][w]; CN += wcn[sc][w]; }
            float ap = SP / (float)(CP > 0 ? CP : 1);
            float an = SN / (float)(CN > 0 ? CN : 1);
            float x  = ap - an;
            lossv[sc] = fmaxf(x, 0.f) + log1pf(expf(-fabsf(x)));
            actv[sc]  = (CP > 0 && CN > 0) ? 1 : 0;
        }
        actv[1] &= actv[0];
        float contrib = (actv[0] ? lossv[0] : 0.f) + (actv[1] ? lossv[1] : 0.f);
        float times   = (float)(actv[0] + actv[1]);
        __hip_atomic_store(&res[2 * blk],     contrib, __ATOMIC_RELAXED, __HIP_MEMORY_SCOPE_AGENT);
        __hip_atomic_store(&res[2 * blk + 1], times,   __ATOMIC_RELAXED, __HIP_MEMORY_SCOPE_AGENT);
        int old = __hip_atomic_fetch_add(counter, 1, __ATOMIC_ACQ_REL, __HIP_MEMORY_SCOPE_AGENT);
        islast = (old == 31) ? 1 : 0;
    }
    __syncthreads();
    if (islast && wid == 0) {
        float total = 0.f, times = 0.f;
        if (lane < 32) {
            total = __hip_atomic_load(&res[2 * lane],     __ATOMIC_RELAXED, __HIP_MEMORY_SCOPE_AGENT);
            times = __hip_atomic_load(&res[2 * lane + 1], __ATOMIC_RELAXED, __HIP_MEMORY_SCOPE_AGENT);
        }
#pragma unroll
        for (int off = 32; off >= 1; off >>= 1) {
            total += __shfl_xor(total, off, 64);
            times += __shfl_xor(times, off, 64);
        }
        if (lane == 0) out[0] = (times > 0.f) ? (total / times) : 0.f;
    }
}

// ---------------------------------------------------------------------------
extern "C" void kernel_launch(void* const* d_in, const int* in_sizes, int n_in,
                              void* d_out, int out_size, void* d_ws, size_t ws_size,
                              hipStream_t stream) {
    const float* sel_s = (const float*)d_in[0];
    const int*   idx_s = (const int*)  d_in[1];
    const float* sel_l = (const float*)d_in[2];
    const int*   idx_l = (const int*)  d_in[3];
    const float* ker_s = (const float*)d_in[4];
    const float* ker_l = (const float*)d_in[5];
    const float* f_k   = (const float*)d_in[6];
    float* out = (float*)d_out;

    char* base = (char*)d_ws;
    size_t o = 0;
    auto alloc = [&](size_t sz) -> char* {
        char* p = base + o;
        o += (sz + 255) & ~(size_t)255;
        return p;
    };
    unsigned char* valid_s = (unsigned char*)alloc(B_ * NVS);
    unsigned char* valid_l = (unsigned char*)alloc(B_ * NVL);
    unsigned char* cv      = (unsigned char*)alloc(CVBYTES);  // cv_s then cv_l
    float* d_s   = (float*)alloc(ROWS_S * sizeof(float));
    float* d_l   = (float*)alloc(ROWS_L * sizeof(float));
    float* res   = (float*)alloc(64 * sizeof(float));
    int*   cnt   = (int*)alloc(sizeof(int));
    unsigned char* cv_s = cv;
    unsigned char* cv_l = cv + L_ * NS;

    k_prep<<<(B_ * NVS + B_ * NVL + 255) / 256, 256, 0, stream>>>(f_k, valid_s, valid_l, cv, cnt);
    k_dist<<<BLKS_S + BLKS_L, 256, 0, stream>>>(sel_s, sel_l, ker_s, ker_l, d_s, d_l, cv_s, cv_l);
    k_stats<<<32, 256, 0, stream>>>(d_s, d_l, idx_s, idx_l, valid_s, valid_l,
                                    cv_s, cv_l, res, cnt, out);
}